// Round 3
// baseline (1704.306 us; speedup 1.0000x reference)
//
#include <hip/hip_runtime.h>
#include <stdint.h>

// ---------------- types ----------------
typedef _Float16 half_t;
typedef _Float16 half8 __attribute__((ext_vector_type(8)));
typedef _Float16 half4 __attribute__((ext_vector_type(4)));
typedef float f32x16 __attribute__((ext_vector_type(16)));
typedef float f32x4  __attribute__((ext_vector_type(4)));

// ---------------- problem constants ----------------
#define OBS_D 128
#define ACT_D 32
#define IN_D  160            // OBS_D + ACT_D
#define H_D   512
#define T_H   63             // horizon
#define NROWS 2048           // B*N = 32*64
#define KTOT  672            // IN_D + H_D
#define KT_ALL 42            // KTOT/16
#define KT_X   10            // IN_D/16
#define KT_H   32            // H_D/16
#define NT_ALL 48            // 1536/32
#define RB     32            // rows per block in recurrent kernel
#define NBLK   64            // NROWS/RB (row-groups)
#define NCB    4             // column-split of the 512 h-dims (128 per block)
#define PRED_ELEMS (NROWS*T_H*OBS_D)   // 16515072 ; hs starts here in d_out

#define ZERO16 {0.f,0.f,0.f,0.f,0.f,0.f,0.f,0.f,0.f,0.f,0.f,0.f,0.f,0.f,0.f,0.f}
#define MFMA16 __builtin_amdgcn_mfma_f32_32x32x16_f16

__device__ __forceinline__ float sigm(float x) {
    return __builtin_amdgcn_rcpf(1.0f + __expf(-x));
}
__device__ __forceinline__ float tanh_f(float x) {
    // robust for large |x|: expf->inf -> rcp->0 -> -1 ; expf->0 -> 2-1 = +1
    return 2.0f * __builtin_amdgcn_rcpf(1.0f + __expf(-2.0f * x)) - 1.0f;
}

// ============================================================================
// pack_w: W = [w_ih | w_hh] (gates x 672) and w_dec (128 x 512) -> fp16
// B-fragment order for mfma_32x32x16: frag[nt][kt][lane][j] = W[n][k],
//   n = nt*32 + (lane&31), k = kt*16 + (lane>>5)*8 + j
// ============================================================================
__global__ void pack_w(const float* __restrict__ w_ih, const float* __restrict__ w_hh,
                       const float* __restrict__ w_dec,
                       half_t* __restrict__ wpack, half_t* __restrict__ wdpack) {
    int idx = blockIdx.x * 256 + threadIdx.x;
    int lane = idx & 63;
    int m = lane & 31;
    int khalf = lane >> 5;
    if (idx < NT_ALL * KT_ALL * 64) {
        int kt = (idx >> 6) % KT_ALL;
        int nt = idx / (64 * KT_ALL);
        int n = nt * 32 + m;
        int k0 = kt * 16 + khalf * 8;
        half8 o;
        #pragma unroll
        for (int j = 0; j < 8; ++j) {
            int k = k0 + j;
            float v = (k < IN_D) ? w_ih[(size_t)n * IN_D + k]
                                 : w_hh[(size_t)n * H_D + (k - IN_D)];
            o[j] = (half_t)v;
        }
        *(half8*)(wpack + (size_t)idx * 8) = o;
    } else {
        int r = idx - NT_ALL * KT_ALL * 64;   // < 8192
        int kt = (r >> 6) % 32;
        int nt = r / (64 * 32);
        int n = nt * 32 + m;                  // output col (0..127)
        int k0 = kt * 16 + khalf * 8;
        half8 o;
        #pragma unroll
        for (int j = 0; j < 8; ++j) o[j] = (half_t)w_dec[(size_t)n * H_D + k0 + j];
        *(half8*)(wdpack + (size_t)r * 8) = o;
    }
}

// ============================================================================
// pack_x: x = concat(obs, act) -> fp16 A-fragment order ; also zeroes flags
// xfrag[rb][t][kt][lane][j] = x[t][row][k], row = rb*32 + (lane&31),
//   k = kt*16 + (lane>>5)*8 + j
// ============================================================================
__global__ void pack_x(const float* __restrict__ obs, const float* __restrict__ act,
                       half_t* __restrict__ xfrag, unsigned* __restrict__ flags) {
    int idx = blockIdx.x * 256 + threadIdx.x;
    if (idx < NBLK * T_H * NCB)   // agent-scope so gru_main's polls see 0
        __hip_atomic_store(&flags[idx], 0u, __ATOMIC_RELAXED, __HIP_MEMORY_SCOPE_AGENT);
    int lane = idx & 63;
    int kt = (idx >> 6) % KT_X;
    int t  = (idx / (64 * KT_X)) % T_H;
    int rb = idx / (64 * KT_X * T_H);
    int m = lane & 31;
    int row = rb * RB + m;
    int b = row >> 6, nn = row & 63;
    int k0 = kt * 16 + (lane >> 5) * 8;
    const float* ob = obs + (((size_t)(b * 64 + t)) * 64 + nn) * OBS_D;  // T=64 in input!
    const float* ac = act + (((size_t)(b * 64 + t)) * 64 + nn) * ACT_D;
    half8 o;
    #pragma unroll
    for (int j = 0; j < 8; ++j) {
        int k = k0 + j;
        float v = (k < OBS_D) ? ob[k] : ac[k - OBS_D];
        o[j] = (half_t)v;
    }
    *(half8*)(xfrag + (size_t)idx * 8) = o;
}

// ============================================================================
// gru_main: 256 blocks x 256 threads (4 waves).
//   rb = blockIdx>>2 : rows rb*32..+32 ; cb = blockIdx&3 : h-dims cb*128..+128.
// LDS = 84 KB > 160/2 KB  =>  hardware CANNOT co-schedule 2 blocks per CU
// => exactly 1 block/CU, 256 CUs active, 504 KB weight stream per CU per step
// (Round-2 lesson: 128 blocks packed 2/CU -> per-CU stream unchanged -> no win).
// Wave w owns dims d = cb*128 + w*32 + [0,32): streams r/z/n -> 4 accumulators.
// Per step: write own 128 h-dims to global hs (agent-scope, it is an output),
// set flag, issue NEXT step's x-part GEMM (independent of h) to hide flag/L3
// latency, wait for 3 partner flags, stage partners' 384 dims into the next
// A-frag LDS buffer. Exchange addresses are fresh per step (R2-validated).
// ============================================================================
__global__ __launch_bounds__(256, 1) void gru_main(
        const half_t* __restrict__ wpack, const half_t* __restrict__ xfrag,
        const float* __restrict__ b_ih, const float* __restrict__ b_hh,
        float* __restrict__ out, unsigned* __restrict__ flags) {
    __shared__ __align__(16) half_t Xbuf[2][KT_X * 512];     // 20 KB (x dbuf)
    __shared__ __align__(16) half_t Abuf[2][KT_H * 512];     // 64 KB (h dbuf)

    const int tid = threadIdx.x;
    const int w = tid >> 6;            // 0..3
    const int lane = tid & 63;
    const int col = lane & 31;
    const int mbase = (lane >> 5) * 4;
    const int rb = blockIdx.x >> 2;
    const int cb = blockIdx.x & 3;

    // zero h buffer 0 (t=0 reads zeros; buffer 1 is fully written before use)
    {
        uint4 zz = {0u, 0u, 0u, 0u};
        uint4* z4 = (uint4*)&Abuf[0][0];
        #pragma unroll
        for (int i = 0; i < 8; ++i) z4[tid + i * 256] = zz;
    }
    // copy x(0) -> Xbuf[0], x(1) -> Xbuf[1]
    {
        const uint4* src = (const uint4*)(xfrag + (size_t)rb * T_H * (KT_X * 512));
        uint4* d0 = (uint4*)&Xbuf[0][0];
        uint4* d1 = (uint4*)&Xbuf[1][0];
        for (int s = tid; s < KT_X * 64; s += 256) {
            d0[s] = src[s];
            d1[s] = src[s + KT_X * 64];
        }
    }

    // per-lane constants
    const int d = cb * 128 + w * 32 + col;    // this wave's h-dim
    const float br = b_ih[d] + b_hh[d];
    const float bz = b_ih[512 + d] + b_hh[512 + d];
    const float bi = b_ih[1024 + d];
    const float bh = b_hh[1024 + d];

    // B-fragment stream bases (element offsets; +512 per kt)
    const int ntr = cb * 4 + w;               // n-tile within a gate (0..15)
    const half_t* wr = wpack + ((size_t)ntr        * KT_ALL) * 512 + lane * 8;
    const half_t* wz = wpack + ((size_t)(16 + ntr) * KT_ALL) * 512 + lane * 8;
    const half_t* wn = wpack + ((size_t)(32 + ntr) * KT_ALL) * 512 + lane * 8;
    const half_t* whr = wr + (size_t)KT_X * 512;
    const half_t* whz = wz + (size_t)KT_X * 512;
    const half_t* whn = wn + (size_t)KT_X * 512;

    const int b_out = rb >> 1;
    const int nn_base = (rb & 1) << 5;

    float h[16];
    #pragma unroll
    for (int i = 0; i < 16; ++i) h[i] = 0.0f;

    // scatter-write constants (C/D reg -> A-frag LDS position); global k = d
    const int lp = 32 * ((col >> 3) & 1);
    const int jj = col & 7;
    const int ktb = d >> 4;                   // h-kt index (0..31), incl. cb offset

    float* hbase = out + (size_t)PRED_ELEMS
                 + ((size_t)b_out * T_H) * (64 * 512) + (size_t)nn_base * 512 + d;

    int p = 0;
    __syncthreads();

    f32x16 ar, az, ai, ah;

#define ACC_INIT() do { _Pragma("unroll") \
    for (int i = 0; i < 16; ++i) { ar[i] = br; az[i] = bz; ai[i] = bi; ah[i] = bh; } \
    } while (0)

#define XPART(XP) do { const half8* Xf = (const half8*)(XP) + lane; \
    _Pragma("unroll") \
    for (int kt = 0; kt < KT_X; ++kt) { \
        half8 a = Xf[kt * 64]; \
        ar = MFMA16(a, *(const half8*)(wr + kt * 512), ar, 0, 0, 0); \
        az = MFMA16(a, *(const half8*)(wz + kt * 512), az, 0, 0, 0); \
        ai = MFMA16(a, *(const half8*)(wn + kt * 512), ai, 0, 0, 0); \
    } } while (0)

    // prologue: acc for t=0
    ACC_INIT();
    XPART(&Xbuf[0][0]);

    for (int t = 0; ; ++t) {
        // h part (LDS buffer p): r, z, gh_n
        {
            const half8* Af = (const half8*)&Abuf[p][0] + lane;
            #pragma unroll 8
            for (int kt = 0; kt < KT_H; ++kt) {
                half8 a = Af[kt * 64];
                ar = MFMA16(a, *(const half8*)(whr + kt * 512), ar, 0, 0, 0);
                az = MFMA16(a, *(const half8*)(whz + kt * 512), az, 0, 0, 0);
                ah = MFMA16(a, *(const half8*)(whn + kt * 512), ah, 0, 0, 0);
            }
        }

        // epilogue: gates -> h update -> global hs store + own scatter to p^1
        {
            float* hp = hbase + (size_t)t * (64 * 512);
            half_t* Ab1 = &Abuf[p ^ 1][0];
            #pragma unroll
            for (int r = 0; r < 16; ++r) {
                int m = (r & 3) + 8 * (r >> 2) + mbase;   // C/D row (verified)
                float rr = sigm(ar[r]);
                float zz2 = sigm(az[r]);
                float nn2 = tanh_f(ai[r] + rr * ah[r]);
                float hv = (1.0f - zz2) * nn2 + zz2 * h[r];
                h[r] = hv;
                __hip_atomic_store(hp + (size_t)m * 512, hv,
                                   __ATOMIC_RELAXED, __HIP_MEMORY_SCOPE_AGENT);
                Ab1[ktb * 512 + (m + lp) * 8 + jj] = (half_t)hv;
            }
        }

        if (t == T_H - 1) break;

        __syncthreads();     // A: all hs stores drained (vmcnt 0 at barrier)

        unsigned* fl = flags + (((size_t)rb * T_H) + t) * NCB;
        if (tid == 0)
            __hip_atomic_store(fl + cb, 1u, __ATOMIC_RELEASE, __HIP_MEMORY_SCOPE_AGENT);

        // overlap: next step's x-part GEMM does not depend on h -> issue now
        ACC_INIT();
        XPART(&Xbuf[(t + 1) & 1][0]);

        // wait for 3 partners (R2-validated relaxed protocol; fresh addresses)
        if (tid < 3) {
            int pc = tid + (tid >= cb);
            int guard = 0;
            while (__hip_atomic_load(fl + pc, __ATOMIC_RELAXED,
                                     __HIP_MEMORY_SCOPE_AGENT) == 0u) {
                if (++guard > (1 << 14)) break;   // fail loud, never hang
            }
        }
        __syncthreads();     // B: partner h(t) visible

        // stage partners' 384 dims -> Abuf[p^1] (disjoint from own 128 dims)
        {
            const float* ph = out + (size_t)PRED_ELEMS
                + ((size_t)b_out * T_H + t) * (64 * 512) + (size_t)nn_base * 512;
            half_t* Ab1 = &Abuf[p ^ 1][0];
            #pragma unroll
            for (int s = 0; s < 12; ++s) {
                int i = tid + s * 256;            // 0..3071 : (row m, 4-dim chunk)
                int m = i / 96;
                int c = i - m * 96;
                int pd = c * 4;                   // 0..380, skip-own remap:
                int d2 = pd + (pd >= cb * 128 ? 128 : 0);
                f32x4 v = *(const f32x4*)(ph + (size_t)m * 512 + d2);
                int kt = d2 >> 4, kh = (d2 >> 3) & 1, j0 = d2 & 7;
                half4 o;
                o[0] = (half_t)v[0]; o[1] = (half_t)v[1];
                o[2] = (half_t)v[2]; o[3] = (half_t)v[3];
                *(half4*)(Ab1 + kt * 512 + kh * 256 + m * 8 + j0) = o;
            }
            // prefetch x(t+2) into the buffer x(t) vacated
            if (t + 2 < T_H) {
                const uint4* src = (const uint4*)(xfrag +
                    ((size_t)rb * T_H + (t + 2)) * (size_t)(KT_X * 512));
                uint4* dst = (uint4*)&Xbuf[t & 1][0];
                for (int s = tid; s < KT_X * 64; s += 256) dst[s] = src[s];
            }
        }
        __syncthreads();     // C: staging visible before next h-part
        p ^= 1;
    }
#undef ACC_INIT
#undef XPART
}

// ============================================================================
// dec_k: preds = hs @ w_dec^T + b_dec.  4032 blocks x 256 threads (4 waves).
// Block: 32 rows; wave w: output cols [w*32, w*32+32).
// ============================================================================
#define DPAD 520   // fp16 row stride (pad 512 -> 520 to break 32-way LDS conflicts)
__global__ __launch_bounds__(256) void dec_k(
        const float* __restrict__ hs, const half_t* __restrict__ wdpack,
        const float* __restrict__ b_dec, float* __restrict__ preds) {
    __shared__ __align__(16) half_t Ab[32 * DPAD];   // 33280 B
    const int tid = threadIdx.x, w = tid >> 6, lane = tid & 63;
    const size_t row0 = (size_t)blockIdx.x * 32;

    // stage 32x512 fp32 -> fp16 row-major (padded) in LDS, coalesced
    const float* src = hs + row0 * 512;
    #pragma unroll
    for (int c = 0; c < 16; ++c) {
        int f = c * 1024 + tid * 4;
        f32x4 v = *(const f32x4*)(src + f);
        int m = f >> 9, colc = f & 511;
        half4 o;
        o[0] = (half_t)v[0]; o[1] = (half_t)v[1]; o[2] = (half_t)v[2]; o[3] = (half_t)v[3];
        *(half4*)(Ab + m * DPAD + colc) = o;
    }
    __syncthreads();

    f32x16 acc = ZERO16;
    const half_t* wd = wdpack + ((size_t)w * 32) * 512 + lane * 8;
    const int mA = lane & 31, k0 = (lane >> 5) * 8;
    #pragma unroll 4
    for (int kt = 0; kt < 32; ++kt) {
        half8 a = *(const half8*)(Ab + mA * DPAD + kt * 16 + k0);
        half8 b = *(const half8*)(wd + kt * 512);
        acc = MFMA16(a, b, acc, 0, 0, 0);
    }
    const int colD = w * 32 + (lane & 31);
    const float bd = b_dec[colD];
    #pragma unroll
    for (int r = 0; r < 16; ++r) {
        int m = (r & 3) + 8 * (r >> 2) + 4 * (lane >> 5);
        preds[(row0 + m) * 128 + colD] = acc[r] + bd;
    }
}

// ============================================================================
extern "C" void kernel_launch(void* const* d_in, const int* in_sizes, int n_in,
                              void* d_out, int out_size, void* d_ws, size_t ws_size,
                              hipStream_t stream) {
    const float* obs   = (const float*)d_in[0];
    const float* act   = (const float*)d_in[1];
    const float* w_ih  = (const float*)d_in[2];
    const float* w_hh  = (const float*)d_in[3];
    const float* b_ih  = (const float*)d_in[4];
    const float* b_hh  = (const float*)d_in[5];
    const float* w_dec = (const float*)d_in[6];
    const float* b_dec = (const float*)d_in[7];
    // d_in[8] = horizon (fixed 63; compiled in)
    float* out = (float*)d_out;

    // workspace layout (fp16 elements): wpack | wdpack | xfrag | flags ~= 43.6 MB
    half_t* wpack  = (half_t*)d_ws;                          // 48*42*512  = 1032192
    half_t* wdpack = wpack + (size_t)NT_ALL * KT_ALL * 512;  // 4*32*512 = 65536
    half_t* xfrag  = wdpack + (size_t)4 * 32 * 512;          // 64*63*5120 = 20643840
    unsigned* flags = (unsigned*)(xfrag + (size_t)NBLK * T_H * (KT_X * 512));

    hipLaunchKernelGGL(pack_w, dim3(536), dim3(256), 0, stream,
                       w_ih, w_hh, w_dec, wpack, wdpack);
    hipLaunchKernelGGL(pack_x, dim3(10080), dim3(256), 0, stream,
                       obs, act, xfrag, flags);
    hipLaunchKernelGGL(gru_main, dim3(NBLK * NCB), dim3(256), 0, stream,
                       wpack, xfrag, b_ih, b_hh, out, flags);
    hipLaunchKernelGGL(dec_k, dim3(NROWS * T_H / 32), dim3(256), 0, stream,
                       out + (size_t)PRED_ELEMS, wdpack, b_dec, out);
}

// Round 5
// 1505.094 us; speedup vs baseline: 1.1324x; 1.1324x over previous
//
#include <hip/hip_runtime.h>
#include <stdint.h>

// ---------------- types ----------------
typedef _Float16 half_t;
typedef _Float16 half8 __attribute__((ext_vector_type(8)));
typedef _Float16 half4 __attribute__((ext_vector_type(4)));
typedef float f32x16 __attribute__((ext_vector_type(16)));
typedef float f32x4  __attribute__((ext_vector_type(4)));

// ---------------- problem constants ----------------
#define OBS_D 128
#define ACT_D 32
#define IN_D  160            // OBS_D + ACT_D
#define H_D   512
#define T_H   63             // horizon
#define NROWS 2048           // B*N = 32*64
#define KTOT  672            // IN_D + H_D
#define KT_ALL 42            // KTOT/16
#define KT_X   10            // IN_D/16
#define KT_H   32            // H_D/16
#define NT_ALL 48            // 1536/32
#define NBLK   64            // 32-row groups for pack_x layout
#define NG     16            // row-groups in gru (128 rows each)
#define NC     16            // col-blocks in gru (32 h-dims each)
#define NFLAG_WORDS (NG*T_H*NC)            // 16128 u32 = 64.5 KB (R3-safe total)
#define PRED_ELEMS (NROWS*T_H*OBS_D)       // 16515072 ; hs starts here in d_out

#define ZERO16 {0.f,0.f,0.f,0.f,0.f,0.f,0.f,0.f,0.f,0.f,0.f,0.f,0.f,0.f,0.f,0.f}
#define MFMA16 __builtin_amdgcn_mfma_f32_32x32x16_f16

__device__ __forceinline__ float sigm(float x) {
    return __builtin_amdgcn_rcpf(1.0f + __expf(-x));
}
__device__ __forceinline__ float tanh_f(float x) {
    // robust for large |x|: expf->inf -> rcp->0 -> -1 ; expf->0 -> 2-1 = +1
    return 2.0f * __builtin_amdgcn_rcpf(1.0f + __expf(-2.0f * x)) - 1.0f;
}

// ============================================================================
// pack_w: W = [w_ih | w_hh] (gates x 672) and w_dec (128 x 512) -> fp16
// B-fragment order for mfma_32x32x16: frag[nt][kt][lane][j] = W[n][k],
//   n = nt*32 + (lane&31), k = kt*16 + (lane>>5)*8 + j
// ============================================================================
__global__ void pack_w(const float* __restrict__ w_ih, const float* __restrict__ w_hh,
                       const float* __restrict__ w_dec,
                       half_t* __restrict__ wpack, half_t* __restrict__ wdpack) {
    int idx = blockIdx.x * 256 + threadIdx.x;
    int lane = idx & 63;
    int m = lane & 31;
    int khalf = lane >> 5;
    if (idx < NT_ALL * KT_ALL * 64) {
        int kt = (idx >> 6) % KT_ALL;
        int nt = idx / (64 * KT_ALL);
        int n = nt * 32 + m;
        int k0 = kt * 16 + khalf * 8;
        half8 o;
        #pragma unroll
        for (int j = 0; j < 8; ++j) {
            int k = k0 + j;
            float v = (k < IN_D) ? w_ih[(size_t)n * IN_D + k]
                                 : w_hh[(size_t)n * H_D + (k - IN_D)];
            o[j] = (half_t)v;
        }
        *(half8*)(wpack + (size_t)idx * 8) = o;
    } else {
        int r = idx - NT_ALL * KT_ALL * 64;   // < 8192
        int kt = (r >> 6) % 32;
        int nt = r / (64 * 32);
        int n = nt * 32 + m;                  // output col (0..127)
        int k0 = kt * 16 + khalf * 8;
        half8 o;
        #pragma unroll
        for (int j = 0; j < 8; ++j) o[j] = (half_t)w_dec[(size_t)n * H_D + k0 + j];
        *(half8*)(wdpack + (size_t)r * 8) = o;
    }
}

// ============================================================================
// pack_x: x = concat(obs, act) -> fp16 A-fragment order ; also zeroes flags
// xfrag[rb][t][kt][lane][j] = x[t][row][k], row = rb*32 + (lane&31),
//   k = kt*16 + (lane>>5)*8 + j
// ============================================================================
__global__ void pack_x(const float* __restrict__ obs, const float* __restrict__ act,
                       half_t* __restrict__ xfrag, unsigned* __restrict__ flags) {
    int idx = blockIdx.x * 256 + threadIdx.x;
    if (idx < NFLAG_WORDS)   // agent-scope so gru_main's polls see 0
        __hip_atomic_store(&flags[idx], 0u, __ATOMIC_RELAXED, __HIP_MEMORY_SCOPE_AGENT);
    int lane = idx & 63;
    int kt = (idx >> 6) % KT_X;
    int t  = (idx / (64 * KT_X)) % T_H;
    int rb = idx / (64 * KT_X * T_H);
    int m = lane & 31;
    int row = rb * 32 + m;
    int b = row >> 6, nn = row & 63;
    int k0 = kt * 16 + (lane >> 5) * 8;
    const float* ob = obs + (((size_t)(b * 64 + t)) * 64 + nn) * OBS_D;  // T=64 in input!
    const float* ac = act + (((size_t)(b * 64 + t)) * 64 + nn) * ACT_D;
    half8 o;
    #pragma unroll
    for (int j = 0; j < 8; ++j) {
        int k = k0 + j;
        float v = (k < OBS_D) ? ob[k] : ac[k - OBS_D];
        o[j] = (half_t)v;
    }
    *(half8*)(xfrag + (size_t)idx * 8) = o;
}

// ============================================================================
// gru_main v4b: 256 blocks x 256 threads (4 waves). Weight-stationary.
//   g  = blockIdx & 15 : row-group (128 rows g*128..+128)
//   cb = blockIdx >> 4 : h-dim slice (32 dims cb*32..+32)
// Under round-robin dispatch all 16 col-blocks of group g land on XCD g%8
// (cb*16+g = g mod 8): h-exchange + flags stay inside one L2 (perf only —
// correctness uses the R2/R3-validated fresh-address device protocol).
// B-slice (r,z,n n-tiles for this 32-dim slice) = 129 KB, LDS-RESIDENT for
// all 63 steps -> zero weight re-streaming; also hardware-forces 1 block/CU.
// Wave wv owns M-tile wv (32 rows): 4 accumulators (ar,az,ai,ah).
// Per step: x-part A from xfrag (L2); h-part A read fp32 from hs(t-1) in the
// out buffer (written by the 16 col-blocks last step), cvt->fp16 in-reg.
// Sync: release-store own flag, 16-lane acquire-poll, 2 barriers/step.
// v4 bugfix: B-slice copy is 2688 uint4/gate (was 1344 -> garbage weights).
// ============================================================================
__global__ __launch_bounds__(256, 1) void gru_main(
        const half_t* __restrict__ wpack, const half_t* __restrict__ xfrag,
        const float* __restrict__ b_ih, const float* __restrict__ b_hh,
        float* __restrict__ out, unsigned* __restrict__ flags) {
    __shared__ __align__(16) half_t Bl[3 * KT_ALL * 512];   // 129024 B -> 1 block/CU

    const int tid = threadIdx.x;
    const int wv = tid >> 6;           // 0..3 (M-tile)
    const int lane = tid & 63;
    const int col = lane & 31;
    const int khalf = lane >> 5;
    const int mbase = khalf * 4;
    const int g  = blockIdx.x & 15;    // row-group
    const int cb = blockIdx.x >> 4;    // column block

    // ---- load B-slice into LDS: gate n-tiles {cb, 16+cb, 32+cb} ----
    // each gate slice = KT_ALL*512 halfs = 2688 uint4
    {
        uint4* dst = (uint4*)Bl;
        #pragma unroll
        for (int gi = 0; gi < 3; ++gi) {
            const uint4* src = (const uint4*)(wpack +
                ((size_t)(gi * 16 + cb) * KT_ALL) * 512);
            for (int s = tid; s < KT_ALL * 64; s += 256)
                dst[gi * (KT_ALL * 64) + s] = src[s];
        }
    }

    // per-lane constants
    const int d = cb * 32 + col;              // this lane's h-dim
    const float br = b_ih[d] + b_hh[d];
    const float bz = b_ih[512 + d] + b_hh[512 + d];
    const float bi = b_ih[1024 + d];
    const float bh = b_hh[1024 + d];

    const int bq  = g * 2 + (wv >> 1);        // batch index of this wave's rows
    const int nnq = (wv & 1) * 32;            // nn offset within batch
    const int rrow = lane & 31;               // row within M-tile

    // x A-frag base (rb group = g*4 + wv)
    const half_t* xb = xfrag + ((size_t)(g * 4 + wv) * T_H) * (KT_X * 512) + lane * 8;

    // hs base (row-major fp32) for this wave's 64-row batch slice
    float* hsw = out + (size_t)PRED_ELEMS
               + ((size_t)bq * T_H) * (64 * 512) + (size_t)nnq * 512;

    float h[16];
    #pragma unroll
    for (int i = 0; i < 16; ++i) h[i] = 0.0f;

    const half8* Br = (const half8*)Bl;                     // [kt*64 + lane]
    const half8* Bz = (const half8*)(Bl + 21504);
    const half8* Bn = (const half8*)(Bl + 43008);

    __syncthreads();

    for (int t = 0; ; ++t) {
        f32x16 ar, az, ai, ah;
        #pragma unroll
        for (int i = 0; i < 16; ++i) { ar[i] = br; az[i] = bz; ai[i] = bi; ah[i] = bh; }

        // ---- x part: r, z, gi_n (A from global xfrag, B from LDS) ----
        {
            const half_t* xt = xb + (size_t)t * (KT_X * 512);
            #pragma unroll
            for (int kt = 0; kt < KT_X; ++kt) {
                half8 a = *(const half8*)(xt + kt * 512);
                ar = MFMA16(a, Br[kt * 64 + lane], ar, 0, 0, 0);
                az = MFMA16(a, Bz[kt * 64 + lane], az, 0, 0, 0);
                ai = MFMA16(a, Bn[kt * 64 + lane], ai, 0, 0, 0);
            }
        }
        // ---- h part: r, z, gh_n (A = fp32 hs(t-1) cvt'd in-reg) ----
        if (t > 0) {
            const float* hp = hsw + (size_t)(t - 1) * (64 * 512)
                            + (size_t)rrow * 512 + khalf * 8;
            #pragma unroll 8
            for (int kt = KT_X; kt < KT_ALL; ++kt) {
                int hd = (kt - KT_X) * 16;
                f32x4 v0 = *(const f32x4*)(hp + hd);
                f32x4 v1 = *(const f32x4*)(hp + hd + 4);
                half8 a;
                a[0] = (half_t)v0[0]; a[1] = (half_t)v0[1];
                a[2] = (half_t)v0[2]; a[3] = (half_t)v0[3];
                a[4] = (half_t)v1[0]; a[5] = (half_t)v1[1];
                a[6] = (half_t)v1[2]; a[7] = (half_t)v1[3];
                ar = MFMA16(a, Br[kt * 64 + lane], ar, 0, 0, 0);
                az = MFMA16(a, Bz[kt * 64 + lane], az, 0, 0, 0);
                ah = MFMA16(a, Bn[kt * 64 + lane], ah, 0, 0, 0);
            }
        }

        // ---- epilogue: gates -> h update -> hs(t) store (agent scope) ----
        {
            float* hw = hsw + (size_t)t * (64 * 512);
            #pragma unroll
            for (int r = 0; r < 16; ++r) {
                int m = (r & 3) + 8 * (r >> 2) + mbase;   // C/D row (verified)
                float rr = sigm(ar[r]);
                float zz2 = sigm(az[r]);
                float nn2 = tanh_f(ai[r] + rr * ah[r]);
                float hv = (1.0f - zz2) * nn2 + zz2 * h[r];
                h[r] = hv;
                __hip_atomic_store(hw + (size_t)m * 512 + d, hv,
                                   __ATOMIC_RELAXED, __HIP_MEMORY_SCOPE_AGENT);
            }
        }

        if (t == T_H - 1) break;

        __syncthreads();   // all waves' hs stores drained (vmcnt 0 at barrier)

        unsigned* fb = flags + (size_t)(g * T_H + t) * NC;   // one 64B line
        if (tid == 0)
            __hip_atomic_store(fb + cb, 1u,
                               __ATOMIC_RELEASE, __HIP_MEMORY_SCOPE_AGENT);
        if (tid < NC) {
            int guard = 0;
            while (__hip_atomic_load(fb + tid, __ATOMIC_ACQUIRE,
                                     __HIP_MEMORY_SCOPE_AGENT) == 0u) {
                if (++guard > (1 << 15)) break;   // fail loud, never hang
            }
        }
        __syncthreads();   // partner hs(t) visible to all threads
    }
}

// ============================================================================
// dec_k: preds = hs @ w_dec^T + b_dec.  4032 blocks x 256 threads (4 waves).
// Block: 32 rows; wave w: output cols [w*32, w*32+32).
// ============================================================================
#define DPAD 520   // fp16 row stride (pad 512 -> 520 to break 32-way LDS conflicts)
__global__ __launch_bounds__(256) void dec_k(
        const float* __restrict__ hs, const half_t* __restrict__ wdpack,
        const float* __restrict__ b_dec, float* __restrict__ preds) {
    __shared__ __align__(16) half_t Ab[32 * DPAD];   // 33280 B
    const int tid = threadIdx.x, w = tid >> 6, lane = tid & 63;
    const size_t row0 = (size_t)blockIdx.x * 32;

    // stage 32x512 fp32 -> fp16 row-major (padded) in LDS, coalesced
    const float* src = hs + row0 * 512;
    #pragma unroll
    for (int c = 0; c < 16; ++c) {
        int f = c * 1024 + tid * 4;
        f32x4 v = *(const f32x4*)(src + f);
        int m = f >> 9, colc = f & 511;
        half4 o;
        o[0] = (half_t)v[0]; o[1] = (half_t)v[1]; o[2] = (half_t)v[2]; o[3] = (half_t)v[3];
        *(half4*)(Ab + m * DPAD + colc) = o;
    }
    __syncthreads();

    f32x16 acc = ZERO16;
    const half_t* wd = wdpack + ((size_t)w * 32) * 512 + lane * 8;
    const int mA = lane & 31, k0 = (lane >> 5) * 8;
    #pragma unroll 4
    for (int kt = 0; kt < 32; ++kt) {
        half8 a = *(const half8*)(Ab + mA * DPAD + kt * 16 + k0);
        half8 b = *(const half8*)(wd + kt * 512);
        acc = MFMA16(a, b, acc, 0, 0, 0);
    }
    const int colD = w * 32 + (lane & 31);
    const float bd = b_dec[colD];
    #pragma unroll
    for (int r = 0; r < 16; ++r) {
        int m = (r & 3) + 8 * (r >> 2) + 4 * (lane >> 5);
        preds[(row0 + m) * 128 + colD] = acc[r] + bd;
    }
}

// ============================================================================
extern "C" void kernel_launch(void* const* d_in, const int* in_sizes, int n_in,
                              void* d_out, int out_size, void* d_ws, size_t ws_size,
                              hipStream_t stream) {
    const float* obs   = (const float*)d_in[0];
    const float* act   = (const float*)d_in[1];
    const float* w_ih  = (const float*)d_in[2];
    const float* w_hh  = (const float*)d_in[3];
    const float* b_ih  = (const float*)d_in[4];
    const float* b_hh  = (const float*)d_in[5];
    const float* w_dec = (const float*)d_in[6];
    const float* b_dec = (const float*)d_in[7];
    // d_in[8] = horizon (fixed 63; compiled in)
    float* out = (float*)d_out;

    // workspace (fp16 elems): wpack | wdpack | xfrag | flags
    // byte total == Round-3 validated footprint (43,547,648 B)
    half_t* wpack  = (half_t*)d_ws;                          // 48*42*512  = 1032192
    half_t* wdpack = wpack + (size_t)NT_ALL * KT_ALL * 512;  // 4*32*512 = 65536
    half_t* xfrag  = wdpack + (size_t)4 * 32 * 512;          // 64*63*5120 = 20643840
    unsigned* flags = (unsigned*)(xfrag + (size_t)NBLK * T_H * (KT_X * 512));

    hipLaunchKernelGGL(pack_w, dim3(536), dim3(256), 0, stream,
                       w_ih, w_hh, w_dec, wpack, wdpack);
    hipLaunchKernelGGL(pack_x, dim3(10080), dim3(256), 0, stream,
                       obs, act, xfrag, flags);
    hipLaunchKernelGGL(gru_main, dim3(NG * NC), dim3(256), 0, stream,
                       wpack, xfrag, b_ih, b_hh, out, flags);
    hipLaunchKernelGGL(dec_k, dim3(NROWS * T_H / 32), dim3(256), 0, stream,
                       out + (size_t)PRED_ELEMS, wdpack, b_dec, out);
}

// Round 6
// 1262.029 us; speedup vs baseline: 1.3504x; 1.1926x over previous
//
#include <hip/hip_runtime.h>
#include <stdint.h>

// ---------------- types ----------------
typedef _Float16 half_t;
typedef _Float16 half8 __attribute__((ext_vector_type(8)));
typedef _Float16 half4 __attribute__((ext_vector_type(4)));
typedef float f32x16 __attribute__((ext_vector_type(16)));
typedef float f32x4  __attribute__((ext_vector_type(4)));

// ---------------- problem constants ----------------
#define OBS_D 128
#define ACT_D 32
#define IN_D  160            // OBS_D + ACT_D
#define H_D   512
#define T_H   63             // horizon
#define NROWS 2048           // B*N = 32*64
#define KTOT  672            // IN_D + H_D
#define KT_ALL 42            // KTOT/16
#define KT_X   10            // IN_D/16
#define KT_H   32            // H_D/16
#define NT_ALL 48            // 1536/32
#define NBLK   64            // 32-row groups for pack_x layout
#define NG     16            // row-groups in gru (128 rows each)
#define NC     16            // col-blocks in gru (32 h-dims each)
#define NFLAG_WORDS (NG*T_H*NC)            // 16128 u32 = 64.5 KB (R3-safe total)
#define PRED_ELEMS (NROWS*T_H*OBS_D)       // 16515072 ; hs starts here in d_out

#define ZERO16 {0.f,0.f,0.f,0.f,0.f,0.f,0.f,0.f,0.f,0.f,0.f,0.f,0.f,0.f,0.f,0.f}
#define MFMA16 __builtin_amdgcn_mfma_f32_32x32x16_f16

__device__ __forceinline__ float sigm(float x) {
    return __builtin_amdgcn_rcpf(1.0f + __expf(-x));
}
__device__ __forceinline__ float tanh_f(float x) {
    // robust for large |x|: expf->inf -> rcp->0 -> -1 ; expf->0 -> 2-1 = +1
    return 2.0f * __builtin_amdgcn_rcpf(1.0f + __expf(-2.0f * x)) - 1.0f;
}

// ============================================================================
// pack_w: W = [w_ih | w_hh] (gates x 672) and w_dec (128 x 512) -> fp16
// B-fragment order for mfma_32x32x16: frag[nt][kt][lane][j] = W[n][k],
//   n = nt*32 + (lane&31), k = kt*16 + (lane>>5)*8 + j
// ============================================================================
__global__ void pack_w(const float* __restrict__ w_ih, const float* __restrict__ w_hh,
                       const float* __restrict__ w_dec,
                       half_t* __restrict__ wpack, half_t* __restrict__ wdpack) {
    int idx = blockIdx.x * 256 + threadIdx.x;
    int lane = idx & 63;
    int m = lane & 31;
    int khalf = lane >> 5;
    if (idx < NT_ALL * KT_ALL * 64) {
        int kt = (idx >> 6) % KT_ALL;
        int nt = idx / (64 * KT_ALL);
        int n = nt * 32 + m;
        int k0 = kt * 16 + khalf * 8;
        half8 o;
        #pragma unroll
        for (int j = 0; j < 8; ++j) {
            int k = k0 + j;
            float v = (k < IN_D) ? w_ih[(size_t)n * IN_D + k]
                                 : w_hh[(size_t)n * H_D + (k - IN_D)];
            o[j] = (half_t)v;
        }
        *(half8*)(wpack + (size_t)idx * 8) = o;
    } else {
        int r = idx - NT_ALL * KT_ALL * 64;   // < 8192
        int kt = (r >> 6) % 32;
        int nt = r / (64 * 32);
        int n = nt * 32 + m;                  // output col (0..127)
        int k0 = kt * 16 + khalf * 8;
        half8 o;
        #pragma unroll
        for (int j = 0; j < 8; ++j) o[j] = (half_t)w_dec[(size_t)n * H_D + k0 + j];
        *(half8*)(wdpack + (size_t)r * 8) = o;
    }
}

// ============================================================================
// pack_x: x = concat(obs, act) -> fp16 A-fragment order ; also zeroes flags
// xfrag[rb][t][kt][lane][j] = x[t][row][k], row = rb*32 + (lane&31),
//   k = kt*16 + (lane>>5)*8 + j
// ============================================================================
__global__ void pack_x(const float* __restrict__ obs, const float* __restrict__ act,
                       half_t* __restrict__ xfrag, unsigned* __restrict__ flags) {
    int idx = blockIdx.x * 256 + threadIdx.x;
    if (idx < NFLAG_WORDS)   // agent-scope so gru_main's polls see 0
        __hip_atomic_store(&flags[idx], 0u, __ATOMIC_RELAXED, __HIP_MEMORY_SCOPE_AGENT);
    int lane = idx & 63;
    int kt = (idx >> 6) % KT_X;
    int t  = (idx / (64 * KT_X)) % T_H;
    int rb = idx / (64 * KT_X * T_H);
    int m = lane & 31;
    int row = rb * 32 + m;
    int b = row >> 6, nn = row & 63;
    int k0 = kt * 16 + (lane >> 5) * 8;
    const float* ob = obs + (((size_t)(b * 64 + t)) * 64 + nn) * OBS_D;  // T=64 in input!
    const float* ac = act + (((size_t)(b * 64 + t)) * 64 + nn) * ACT_D;
    half8 o;
    #pragma unroll
    for (int j = 0; j < 8; ++j) {
        int k = k0 + j;
        float v = (k < OBS_D) ? ob[k] : ac[k - OBS_D];
        o[j] = (half_t)v;
    }
    *(half8*)(xfrag + (size_t)idx * 8) = o;
}

// ============================================================================
// gru_main v6: weight-stationary (R5 topology) + latency-depth fixes.
//   g  = blockIdx & 15 : row-group (128 rows) ; cb = blockIdx >> 4 : 32 dims.
// R5 measured 45k cyc/step with <8k of work: residual = h-load latency at
// pipeline depth ~2 (VGPR-starved) + per-iteration acquire invalidations.
// v6: (1) explicit 8-kt software pipeline on hs(t-1) loads (va/vb[8], static
// indices) -> ~16 loads in flight; (2) RELAXED poll, no acquire/fence (safe:
// producer barrier drains vmcnt on sc1 stores before flag store; consumer
// data addresses are fresh per t, so plain loads cannot hit stale lines);
// (3) RELAXED flag store (completion-ordered by the barrier, no wb needed);
// (4) next step's x-part + acc-init run in the release->poll window.
// ============================================================================
__global__ __launch_bounds__(256, 1) void gru_main(
        const half_t* __restrict__ wpack, const half_t* __restrict__ xfrag,
        const float* __restrict__ b_ih, const float* __restrict__ b_hh,
        float* __restrict__ out, unsigned* __restrict__ flags) {
    __shared__ __align__(16) half_t Bl[3 * KT_ALL * 512];   // 129024 B -> 1 block/CU

    const int tid = threadIdx.x;
    const int wv = tid >> 6;           // 0..3 (M-tile)
    const int lane = tid & 63;
    const int col = lane & 31;
    const int khalf = lane >> 5;
    const int mbase = khalf * 4;
    const int g  = blockIdx.x & 15;    // row-group
    const int cb = blockIdx.x >> 4;    // column block

    // ---- load B-slice into LDS: gate n-tiles {cb, 16+cb, 32+cb} ----
    {
        uint4* dst = (uint4*)Bl;
        #pragma unroll
        for (int gi = 0; gi < 3; ++gi) {
            const uint4* src = (const uint4*)(wpack +
                ((size_t)(gi * 16 + cb) * KT_ALL) * 512);
            for (int s = tid; s < KT_ALL * 64; s += 256)
                dst[gi * (KT_ALL * 64) + s] = src[s];
        }
    }

    // per-lane constants
    const int d = cb * 32 + col;              // this lane's h-dim
    const float br = b_ih[d] + b_hh[d];
    const float bz = b_ih[512 + d] + b_hh[512 + d];
    const float bi = b_ih[1024 + d];
    const float bh = b_hh[1024 + d];

    const int bq  = g * 2 + (wv >> 1);        // batch index of this wave's rows
    const int nnq = (wv & 1) * 32;            // nn offset within batch
    const int rrow = lane & 31;               // row within M-tile

    // x A-frag base (rb group = g*4 + wv)
    const half_t* xb = xfrag + ((size_t)(g * 4 + wv) * T_H) * (KT_X * 512) + lane * 8;

    // hs base (row-major fp32) for this wave's 64-row batch slice
    float* hsw = out + (size_t)PRED_ELEMS
               + ((size_t)bq * T_H) * (64 * 512) + (size_t)nnq * 512;

    float h[16];
    #pragma unroll
    for (int i = 0; i < 16; ++i) h[i] = 0.0f;

    const half8* Br = (const half8*)Bl;                     // [kt*64 + lane]
    const half8* Bz = (const half8*)(Bl + 21504);
    const half8* Bn = (const half8*)(Bl + 43008);

    f32x16 ar, az, ai, ah;

#define ACC_INIT() do { _Pragma("unroll") \
    for (int i_ = 0; i_ < 16; ++i_) { ar[i_]=br; az[i_]=bz; ai[i_]=bi; ah[i_]=bh; } \
    } while (0)

#define XPART(TT) do { const half_t* xt_ = xb + (size_t)(TT) * (KT_X * 512); \
    _Pragma("unroll") \
    for (int kt_ = 0; kt_ < KT_X; ++kt_) { \
        half8 a_ = *(const half8*)(xt_ + kt_ * 512); \
        ar = MFMA16(a_, Br[kt_ * 64 + lane], ar, 0, 0, 0); \
        az = MFMA16(a_, Bz[kt_ * 64 + lane], az, 0, 0, 0); \
        ai = MFMA16(a_, Bn[kt_ * 64 + lane], ai, 0, 0, 0); \
    } } while (0)

    __syncthreads();        // Bl staged

    ACC_INIT();
    XPART(0);               // t=0 x-part (h=0: gh_n contribution is exactly bh)

    for (int t = 0; ; ++t) {
        // ---- h part: A = fp32 hs(t-1), software-pipelined 8 kt deep ----
        if (t > 0) {
            const float* hp = hsw + (size_t)(t - 1) * (64 * 512)
                            + (size_t)rrow * 512 + khalf * 8;
            f32x4 va[8], vb[8];
            #pragma unroll
            for (int i = 0; i < 8; ++i) {
                va[i] = *(const f32x4*)(hp + i * 16);
                vb[i] = *(const f32x4*)(hp + i * 16 + 4);
            }
            #pragma unroll
            for (int blk = 0; blk < 4; ++blk) {
                #pragma unroll
                for (int i = 0; i < 8; ++i) {
                    const int kt = blk * 8 + i;          // h-kt 0..31 (static)
                    f32x4 nva, nvb;
                    if (blk < 3) {                       // issue next-blk loads first
                        nva = *(const f32x4*)(hp + (kt + 8) * 16);
                        nvb = *(const f32x4*)(hp + (kt + 8) * 16 + 4);
                    }
                    half8 a;
                    a[0]=(half_t)va[i][0]; a[1]=(half_t)va[i][1];
                    a[2]=(half_t)va[i][2]; a[3]=(half_t)va[i][3];
                    a[4]=(half_t)vb[i][0]; a[5]=(half_t)vb[i][1];
                    a[6]=(half_t)vb[i][2]; a[7]=(half_t)vb[i][3];
                    ar = MFMA16(a, Br[(KT_X + kt) * 64 + lane], ar, 0, 0, 0);
                    az = MFMA16(a, Bz[(KT_X + kt) * 64 + lane], az, 0, 0, 0);
                    ah = MFMA16(a, Bn[(KT_X + kt) * 64 + lane], ah, 0, 0, 0);
                    if (blk < 3) { va[i] = nva; vb[i] = nvb; }
                }
            }
        }

        // ---- epilogue: gates -> h update -> hs(t) store (sc1 write-through) ----
        {
            float* hw = hsw + (size_t)t * (64 * 512);
            #pragma unroll
            for (int r = 0; r < 16; ++r) {
                int m = (r & 3) + 8 * (r >> 2) + mbase;   // C/D row (verified)
                float rr = sigm(ar[r]);
                float zz2 = sigm(az[r]);
                float nn2 = tanh_f(ai[r] + rr * ah[r]);
                float hv = (1.0f - zz2) * nn2 + zz2 * h[r];
                h[r] = hv;
                __hip_atomic_store(hw + (size_t)m * 512 + d, hv,
                                   __ATOMIC_RELAXED, __HIP_MEMORY_SCOPE_AGENT);
            }
        }

        if (t == T_H - 1) break;

        __syncthreads();   // every wave's sc1 stores complete (vmcnt 0) -> visible

        unsigned* fb = flags + (size_t)(g * T_H + t) * NC;   // one 64B line
        if (tid == 0)      // ordered after data by COMPLETION, not by fence
            __hip_atomic_store(fb + cb, 1u,
                               __ATOMIC_RELAXED, __HIP_MEMORY_SCOPE_AGENT);

        // overlap: next step's x-part (independent of h) hides rendezvous skew
        ACC_INIT();
        XPART(t + 1);

        if (tid < NC) {    // relaxed poll: sc1 loads read the coherence point
            int guard = 0;
            while (__hip_atomic_load(fb + tid, __ATOMIC_RELAXED,
                                     __HIP_MEMORY_SCOPE_AGENT) == 0u) {
                if (++guard > (1 << 16)) break;   // fail loud, never hang
            }
        }
        __syncthreads();   // partner hs(t) globally visible; fresh addrs -> no fence
    }
#undef ACC_INIT
#undef XPART
}

// ============================================================================
// dec_k: preds = hs @ w_dec^T + b_dec.  4032 blocks x 256 threads (4 waves).
// Block: 32 rows; wave w: output cols [w*32, w*32+32).
// ============================================================================
#define DPAD 520   // fp16 row stride (pad 512 -> 520 to break 32-way LDS conflicts)
__global__ __launch_bounds__(256) void dec_k(
        const float* __restrict__ hs, const half_t* __restrict__ wdpack,
        const float* __restrict__ b_dec, float* __restrict__ preds) {
    __shared__ __align__(16) half_t Ab[32 * DPAD];   // 33280 B
    const int tid = threadIdx.x, w = tid >> 6, lane = tid & 63;
    const size_t row0 = (size_t)blockIdx.x * 32;

    // stage 32x512 fp32 -> fp16 row-major (padded) in LDS, coalesced
    const float* src = hs + row0 * 512;
    #pragma unroll
    for (int c = 0; c < 16; ++c) {
        int f = c * 1024 + tid * 4;
        f32x4 v = *(const f32x4*)(src + f);
        int m = f >> 9, colc = f & 511;
        half4 o;
        o[0] = (half_t)v[0]; o[1] = (half_t)v[1]; o[2] = (half_t)v[2]; o[3] = (half_t)v[3];
        *(half4*)(Ab + m * DPAD + colc) = o;
    }
    __syncthreads();

    f32x16 acc = ZERO16;
    const half_t* wd = wdpack + ((size_t)w * 32) * 512 + lane * 8;
    const int mA = lane & 31, k0 = (lane >> 5) * 8;
    #pragma unroll 4
    for (int kt = 0; kt < 32; ++kt) {
        half8 a = *(const half8*)(Ab + mA * DPAD + kt * 16 + k0);
        half8 b = *(const half8*)(wd + kt * 512);
        acc = MFMA16(a, b, acc, 0, 0, 0);
    }
    const int colD = w * 32 + (lane & 31);
    const float bd = b_dec[colD];
    #pragma unroll
    for (int r = 0; r < 16; ++r) {
        int m = (r & 3) + 8 * (r >> 2) + 4 * (lane >> 5);
        preds[(row0 + m) * 128 + colD] = acc[r] + bd;
    }
}

// ============================================================================
extern "C" void kernel_launch(void* const* d_in, const int* in_sizes, int n_in,
                              void* d_out, int out_size, void* d_ws, size_t ws_size,
                              hipStream_t stream) {
    const float* obs   = (const float*)d_in[0];
    const float* act   = (const float*)d_in[1];
    const float* w_ih  = (const float*)d_in[2];
    const float* w_hh  = (const float*)d_in[3];
    const float* b_ih  = (const float*)d_in[4];
    const float* b_hh  = (const float*)d_in[5];
    const float* w_dec = (const float*)d_in[6];
    const float* b_dec = (const float*)d_in[7];
    // d_in[8] = horizon (fixed 63; compiled in)
    float* out = (float*)d_out;

    // workspace (fp16 elems): wpack | wdpack | xfrag | flags
    // byte total == Round-3/5 validated footprint
    half_t* wpack  = (half_t*)d_ws;                          // 48*42*512  = 1032192
    half_t* wdpack = wpack + (size_t)NT_ALL * KT_ALL * 512;  // 4*32*512 = 65536
    half_t* xfrag  = wdpack + (size_t)4 * 32 * 512;          // 64*63*5120 = 20643840
    unsigned* flags = (unsigned*)(xfrag + (size_t)NBLK * T_H * (KT_X * 512));

    hipLaunchKernelGGL(pack_w, dim3(536), dim3(256), 0, stream,
                       w_ih, w_hh, w_dec, wpack, wdpack);
    hipLaunchKernelGGL(pack_x, dim3(10080), dim3(256), 0, stream,
                       obs, act, xfrag, flags);
    hipLaunchKernelGGL(gru_main, dim3(NG * NC), dim3(256), 0, stream,
                       wpack, xfrag, b_ih, b_hh, out, flags);
    hipLaunchKernelGGL(dec_k, dim3(NROWS * T_H / 32), dim3(256), 0, stream,
                       out + (size_t)PRED_ELEMS, wdpack, b_dec, out);
}